// Round 3
// baseline (1258.766 us; speedup 1.0000x reference)
//
#include <hip/hip_runtime.h>
#include <hip/hip_bf16.h>
#include <type_traits>

#define T_    1000
#define NB    256
#define HH    64
#define GG    256

typedef float f32x4 __attribute__((ext_vector_type(4)));
typedef __bf16 bf16x8 __attribute__((ext_vector_type(8)));

// Barrier that does NOT drain vmcnt (plain __syncthreads emits s_waitcnt vmcnt(0)
// which would stall on global h-stores and x-prefetch every step).
__device__ __forceinline__ void barrier_lds() {
    asm volatile("s_waitcnt lgkmcnt(0)\n\ts_barrier" ::: "memory");
}

__device__ __forceinline__ float fast_sigmoid(float x) {
    float e = __expf(-x);
    return __builtin_amdgcn_rcpf(1.f + e);
}
__device__ __forceinline__ float fast_tanh(float x) {
    x = fmaxf(x, -15.f);
    float e = __expf(-2.f * x);
    return (1.f - e) * __builtin_amdgcn_rcpf(1.f + e);
}
__device__ __forceinline__ float bf2f(unsigned short u) {
    return __builtin_bit_cast(float, (unsigned)u << 16);
}

// ---------------------------------------------------------------- weight prep
__global__ void prep_w(const float* __restrict__ wihf, const float* __restrict__ wihr,
                       const float* __restrict__ whh, const float* __restrict__ bih,
                       const float* __restrict__ bhh,
                       __bf16* __restrict__ w0H, __bf16* __restrict__ w0L,
                       __bf16* __restrict__ wrH, __bf16* __restrict__ whH,
                       float* __restrict__ bias, float* __restrict__ w0f) {
    int i = blockIdx.x * 256 + threadIdx.x;
    if (i < 2 * GG * 32) {
        int k = i & 31, gd = i >> 5;
        float w = (k < 22) ? wihf[gd * 22 + k] : 0.f;
        __bf16 h = (__bf16)w;
        w0H[i] = h; w0L[i] = (__bf16)(w - (float)h);
        w0f[i] = w;
    }
    if (i < 3 * 2 * GG * 128) wrH[i] = (__bf16)wihr[i];
    if (i < 4 * 2 * GG * HH)  whH[i] = (__bf16)whh[i];
    if (i < 4 * 2 * GG)       bias[i] = bih[i] + bhh[i];
}

// ---------------------------------------------------------------- x prep, hi/lo bf16 planes (layer 0)
__global__ __launch_bounds__(256) void prep_x_ps(const float* __restrict__ x,
                                                 __bf16* __restrict__ xhi,
                                                 __bf16* __restrict__ xlo) {
    const int b = blockIdx.x;
    __shared__ float xs[22][104];
    for (int tc = 0; tc < 10; ++tc) {
        const int t0 = tc * 100;
        __syncthreads();
        for (int i = threadIdx.x; i < 22 * 100; i += 256) {
            int k = i / 100, t = i - k * 100;
            xs[k][t] = x[((size_t)b * 22 + k) * T_ + t0 + t];
        }
        __syncthreads();
        for (int i = threadIdx.x; i < 100 * 4; i += 256) {
            int t = i >> 2, p = i & 3;
            bf16x8 vh, vl;
            #pragma unroll
            for (int j = 0; j < 8; ++j) {
                int k = p * 8 + j;
                float f = (k < 22) ? xs[k][t] : 0.f;
                __bf16 h = (__bf16)f;
                vh[j] = h;
                vl[j] = (__bf16)(f - (float)h);
            }
            *(bf16x8*)(xhi + ((size_t)b * T_ + t0 + t) * 32 + p * 8) = vh;
            *(bf16x8*)(xlo + ((size_t)b * T_ + t0 + t) * 32 + p * 8) = vl;
        }
    }
}

// ---------------------------------------------------------------- x prep single bf16 plane (fallback)
__global__ __launch_bounds__(256) void prep_x_b(const float* __restrict__ x,
                                                __bf16* __restrict__ xp) {
    const int b = blockIdx.x;
    __shared__ float xs[22][104];
    for (int tc = 0; tc < 10; ++tc) {
        const int t0 = tc * 100;
        __syncthreads();
        for (int i = threadIdx.x; i < 22 * 100; i += 256) {
            int k = i / 100, t = i - k * 100;
            xs[k][t] = x[((size_t)b * 22 + k) * T_ + t0 + t];
        }
        __syncthreads();
        for (int i = threadIdx.x; i < 100 * 4; i += 256) {
            int t = i >> 2, p = i & 3;
            bf16x8 v;
            #pragma unroll
            for (int j = 0; j < 8; ++j) {
                int k = p * 8 + j;
                v[j] = (k < 22) ? (__bf16)xs[k][t] : (__bf16)0.f;
            }
            *(bf16x8*)(xp + ((size_t)b * T_ + t0 + t) * 32 + p * 8) = v;
        }
    }
}

// ---------------------------------------------------------------- MFMA fused layer, 2 chains/block (r13 shape)
// r16: VALU/accvgpr-pressure attack on the r15 structure.
//  - R-chain takes Pu as MFMA C-in: iv..ov = R[F][r] directly (no Pu extract+add).
//  - Pu/Pn role ping-pong via alternating GROUP calls (no 16-reg rotation copy);
//    retired accumulator re-inited from resident bias-splat f32x4.
//  - KCH=4 layers: wih weights streamed from LDS (staged once, 272B padded rows)
//    with a 1-step-ahead register prefetch; frees 64 VGPRs so accumulators can
//    live in arch VGPRs (r15: VGPR_Count=120 < resident operand need -> AGPR
//    parking => accvgpr_read/write storm = the unexplained VALUBusy).
//  - FLUSH spread 1 store/step (ping-pong hsave), issue_x spread at u==1,2:
//    fills the post-barrier ds_read latency window every step.
template<int KCH, bool L0, bool FIN>
__global__ __launch_bounds__(256, 1) void fused_scan3(
    const __bf16* __restrict__ inA,   // (B,T,KCH*32) bf16 (hi plane if L0)
    const __bf16* __restrict__ inB,   // lo plane (iff L0)
    const __bf16* __restrict__ wihH,  // (2,256,KCH*32) bf16 hi
    const __bf16* __restrict__ wihL,  // same, lo (iff L0)
    const __bf16* __restrict__ whhH,  // (2,256,64) bf16
    const float*  __restrict__ bias,  // (2,256) f32
    __bf16* __restrict__ out,         // (B,T,128) bf16
    float* __restrict__ outF)         // (B,128) f32 last-t h (iff FIN)
{
    const int dir = blockIdx.y;
    const int b0 = blockIdx.x * 2;
    const int tid = threadIdx.x;
    const int wv = tid >> 6, lane = tid & 63;
    const int j2 = lane & 15, q = lane >> 4;
    const int ch_l = j2 >> 3;          // chain of this lane's A-row
    const int u_l = j2 & 7;            // step-in-group of this lane's A-row
    constexpr int KIN = KCH * 32;

    __shared__ __align__(16) __bf16 hbuf[2][2][80]; // [parity][chain][j pad]
    // padded weight stage for KCH=4: 256 rows x 136 bf16 (272B, 2-way-max banks)
    __shared__ __align__(16) __bf16 wlds[L0 ? 16 : 256 * 136];

    const f32x4 Z4 = (f32x4){0.f, 0.f, 0.f, 0.f};

    // stage wih into LDS (KCH=4 path), linear coalesced copy
    if constexpr (!L0) {
        const __bf16* src = wihH + (size_t)dir * GG * KIN;
        #pragma unroll
        for (int it = 0; it < 16; ++it) {
            int idx = it * 256 + tid;           // 8-elem chunk id, 4096 total
            int row = idx >> 4, cw = idx & 15;
            *(bf16x8*)(&wlds[row * 136 + cw * 8]) = *(const bf16x8*)(src + (size_t)idx * 8);
        }
    }

    bf16x8 wf[L0 ? 4 : 1][L0 ? KCH : 1], wfl[4][L0 ? KCH : 1];
    bf16x8 whf[4][2];
    f32x4 bias4[4];
    #pragma unroll
    for (int F = 0; F < 4; ++F) {
        const int g = (F * 4 + wv) * 16 + j2;
        float bg = bias[dir * GG + g];
        bias4[F] = (f32x4){bg, bg, bg, bg};
        if constexpr (L0) {
            #pragma unroll
            for (int ks = 0; ks < KCH; ++ks) {
                wf[F][ks] = *(const bf16x8*)(wihH + ((size_t)dir * GG + g) * KIN + ks * 32 + q * 8);
                wfl[F][ks] = *(const bf16x8*)(wihL + ((size_t)dir * GG + g) * KIN + ks * 32 + q * 8);
            }
        }
        #pragma unroll
        for (int ks = 0; ks < 2; ++ks)
            whf[F][ks] = *(const bf16x8*)(whhH + ((size_t)dir * GG + g) * HH + ks * 32 + q * 8);
    }
    if (tid < 64) {
        hbuf[1][0][tid] = (__bf16)0.f;
        hbuf[1][1][tid] = (__bf16)0.f;
    }
    __syncthreads();

    // per-lane base index into wlds (elements)
    const int wbase = (wv * 16 + j2) * 136 + q * 8;

    // double-buffered x fragments
    bf16x8 xfA[KCH], xfB[KCH];
    bf16x8 xlA[L0 ? KCH : 1], xlB[L0 ? KCH : 1];
    auto issue_x = [&](int grp, auto& dh, auto& dl) {
        int s = grp * 8 + u_l;
        if (s > T_ - 1) s = T_ - 1;
        int tt = dir ? (T_ - 1) - s : s;
        const __bf16* ph = inA + ((size_t)(b0 + ch_l) * T_ + tt) * KIN + q * 8;
        #pragma unroll
        for (int ks = 0; ks < KCH; ++ks)
            dh[ks] = *(const bf16x8*)(ph + ks * 32);
        if constexpr (L0) {
            const __bf16* pl = inB + ((size_t)(b0 + ch_l) * T_ + tt) * KIN + q * 8;
            #pragma unroll
            for (int ks = 0; ks < KCH; ++ks)
                dl[ks] = *(const bf16x8*)(pl + ks * 32);
        }
    };

    // ---- prologue: P(0) into PuA (bias-init), prefetch x(1) into xfB
    f32x4 PuA[4], PuB[4];
    #pragma unroll
    for (int F = 0; F < 4; ++F) { PuA[F] = bias4[F]; PuB[F] = bias4[F]; }
    issue_x(0, xfA, xlA);
    if constexpr (L0) {
        #pragma unroll
        for (int F = 0; F < 4; ++F)
            PuA[F] = __builtin_amdgcn_mfma_f32_16x16x32_bf16(xfA[0], wf[F][0], PuA[F], 0, 0, 0);
        #pragma unroll
        for (int F = 0; F < 4; ++F)
            PuA[F] = __builtin_amdgcn_mfma_f32_16x16x32_bf16(xlA[0], wf[F][0], PuA[F], 0, 0, 0);
        #pragma unroll
        for (int F = 0; F < 4; ++F)
            PuA[F] = __builtin_amdgcn_mfma_f32_16x16x32_bf16(xfA[0], wfl[F][0], PuA[F], 0, 0, 0);
    } else {
        #pragma unroll
        for (int ks = 0; ks < KCH; ++ks)
            #pragma unroll
            for (int F = 0; F < 4; ++F) {
                bf16x8 w = *(const bf16x8*)&wlds[wbase + F * 8704 + ks * 32];
                PuA[F] = __builtin_amdgcn_mfma_f32_16x16x32_bf16(xfA[ks], w, PuA[F], 0, 0, 0);
            }
    }
    issue_x(1, xfB, xlB);

    // resident u==0 streamed-weight pair (constant across groups), rotating prefetch
    bf16x8 w00, w01, wp[2][2];
    if constexpr (!L0) {
        w00 = *(const bf16x8*)&wlds[wbase];
        w01 = *(const bf16x8*)&wlds[wbase + 8704];
    }

    float hsA[8], hsB[8];
    float creg = 0.f;

    // one 8-step group.  xc = x(grp+1) (feeds Pnx), xn = buffer for x(grp+2).
    // Pc = P(grp)+bias (consumed as R C-in), Pnx = accumulator for P(grp+1).
    // hsC = this group's h regs, hsP = previous group's (flushed 1/step).
    auto GROUP = [&](int grp, auto& xcH, auto& xnH, auto& xcL, auto& xnL,
                     f32x4 (&Pc)[4], f32x4 (&Pnx)[4],
                     float (&hsC)[8], float (&hsP)[8]) {
        const bool doflush = grp > 0;
        const int ch = q >> 1;
        const ptrdiff_t fstep = dir ? -128 : 128;
        const int bt = dir ? (T_ - 1) - (grp - 1) * 8 : (grp - 1) * 8;
        __bf16* fb = out + ((size_t)(b0 + ch) * T_ + bt) * 128
                         + (size_t)dir * HH + wv * 16 + j2;
        #pragma unroll
        for (int u = 0; u < 8; ++u) {
            const int rp = (u + 1) & 1;
            // h ds_reads first (critical chain root)
            bf16x8 ah0 = *(const bf16x8*)&hbuf[rp][ch_l][q * 8];
            bf16x8 ah1 = *(const bf16x8*)&hbuf[rp][ch_l][32 + q * 8];

            // prefetch next step's streamed-weight pair (off critical path)
            if constexpr (!L0) {
                if (u < 7) {
                    const int un = u + 1, ksn = un >> 1, Fbn = (un & 1) * 2;
                    wp[un & 1][0] = *(const bf16x8*)&wlds[wbase + Fbn * 8704 + ksn * 32];
                    wp[un & 1][1] = *(const bf16x8*)&wlds[wbase + (Fbn + 1) * 8704 + ksn * 32];
                }
            }

            // spread flush: one store of prev group's h per step (same owner mask)
            if (doflush && ((q & 1) == (u >> 2))) {
                fb[(ptrdiff_t)u * fstep] = (__bf16)hsP[u];
                if constexpr (FIN)
                    if (u == 0 && dir == 1 && grp == 1)
                        outF[(size_t)(b0 + ch) * 128 + HH + wv * 16 + j2] = hsP[0];
            }

            // spread x prefetch for grp+2
            if constexpr (L0) {
                if (u == 1) issue_x(grp + 2, xnH, xnL);
            } else {
                if (u == 1 || u == 2) issue_x(grp + 2, xnH, xnL);  // compiler CSEs addr
            }

            // Pn pipeline (independent -> fills ds latency)
            if constexpr (!L0) {
                const int ks = u >> 1;
                const int Fb = (u & 1) * 2;
                bf16x8 pw0 = (u == 0) ? w00 : wp[u & 1][0];
                bf16x8 pw1 = (u == 0) ? w01 : wp[u & 1][1];
                Pnx[Fb]     = __builtin_amdgcn_mfma_f32_16x16x32_bf16(xcH[ks], pw0, Pnx[Fb], 0, 0, 0);
                Pnx[Fb + 1] = __builtin_amdgcn_mfma_f32_16x16x32_bf16(xcH[ks], pw1, Pnx[Fb + 1], 0, 0, 0);
            } else {
                if (u == 0) {
                    #pragma unroll
                    for (int F = 0; F < 4; ++F)
                        Pnx[F] = __builtin_amdgcn_mfma_f32_16x16x32_bf16(xcH[0], wf[F][0], Pnx[F], 0, 0, 0);
                } else if (u == 1) {
                    #pragma unroll
                    for (int F = 0; F < 4; ++F)
                        Pnx[F] = __builtin_amdgcn_mfma_f32_16x16x32_bf16(xcL[0], wf[F][0], Pnx[F], 0, 0, 0);
                } else if (u == 2) {
                    #pragma unroll
                    for (int F = 0; F < 4; ++F)
                        Pnx[F] = __builtin_amdgcn_mfma_f32_16x16x32_bf16(xcH[0], wfl[F][0], Pnx[F], 0, 0, 0);
                }
            }

            // recurrent MFMAs with P+bias as C-in: gates come out of one acc quad
            f32x4 R[4];
            #pragma unroll
            for (int F = 0; F < 4; ++F) {
                f32x4 t = __builtin_amdgcn_mfma_f32_16x16x32_bf16(ah0, whf[F][0], Pc[F], 0, 0, 0);
                R[F] = __builtin_amdgcn_mfma_f32_16x16x32_bf16(ah1, whf[F][1], t, 0, 0, 0);
            }

            const int r = u & 3;
            float cold = creg;
            float iv = R[0][r];
            float fv = R[1][r];
            float gv = R[2][r];
            float ov = R[3][r];
            float cn = fast_sigmoid(fv) * cold + fast_sigmoid(iv) * fast_tanh(gv);
            float hn = fast_sigmoid(ov) * fast_tanh(cn);
            // c-handoff between q-lane-halves via lane^16 swizzle
            if (u == 3 || u == 7)
                creg = __builtin_bit_cast(float,
                        __builtin_amdgcn_ds_swizzle(__builtin_bit_cast(int, cn), 0x401F));
            else
                creg = cn;
            const bool owner = ((q & 1) == (u >> 2));
            if (owner) {
                hbuf[u & 1][ch][wv * 16 + j2] = (__bf16)hn;
                hsC[u] = hn;
            }
            barrier_lds();
        }
        // retire Pc: becomes next group's fresh accumulator (bias pre-folded)
        #pragma unroll
        for (int F = 0; F < 4; ++F) Pc[F] = bias4[F];
    };

    for (int g2 = 0; g2 < 62; ++g2) {
        GROUP(g2 * 2,     xfB, xfA, xlB, xlA, PuA, PuB, hsA, hsB);
        GROUP(g2 * 2 + 1, xfA, xfB, xlA, xlB, PuB, PuA, hsB, hsA);
    }
    GROUP(124, xfB, xfA, xlB, xlA, PuA, PuB, hsA, hsB);

    // epilogue: flush group 124 + FIN dir0
    {
        const int ch = q >> 1;
        const ptrdiff_t fstep = dir ? -128 : 128;
        const int bt = dir ? (T_ - 1) - 124 * 8 : 124 * 8;
        __bf16* fb = out + ((size_t)(b0 + ch) * T_ + bt) * 128
                         + (size_t)dir * HH + wv * 16 + j2;
        #pragma unroll
        for (int u = 0; u < 8; ++u)
            if ((q & 1) == (u >> 2)) fb[(ptrdiff_t)u * fstep] = (__bf16)hsA[u];
        if constexpr (FIN)
            if (dir == 0 && ((q & 1) == 1))
                outF[(size_t)(b0 + ch) * 128 + wv * 16 + j2] = hsA[7];
    }
}

// ---------------------------------------------------------------- VALU fallback scan (r7-proven)
template<int KIN, typename TI, typename TO>
__global__ __launch_bounds__(256, 2) void scan_valu(
    const TI* __restrict__ in, const float* __restrict__ wih,
    const float* __restrict__ whh, const float* __restrict__ bias,
    TO* __restrict__ out)
{
    const int dir = blockIdx.y, bb = blockIdx.x, g = threadIdx.x;
    __shared__ __align__(16) float xs[8][KIN];
    __shared__ __align__(16) float act[256];
    __shared__ __align__(16) float hs[2][64];

    float wk[KIN], wr[64];
    {
        const float* wp = wih + (size_t)(dir * GG + g) * KIN;
        #pragma unroll
        for (int k4 = 0; k4 < KIN / 4; ++k4) {
            f32x4 v = *(const f32x4*)(wp + k4 * 4);
            wk[k4 * 4 + 0] = v.x; wk[k4 * 4 + 1] = v.y;
            wk[k4 * 4 + 2] = v.z; wk[k4 * 4 + 3] = v.w;
        }
        const float* rp = whh + (size_t)(dir * GG + g) * HH;
        #pragma unroll
        for (int j4 = 0; j4 < 16; ++j4) {
            f32x4 v = *(const f32x4*)(rp + j4 * 4);
            wr[j4 * 4 + 0] = v.x; wr[j4 * 4 + 1] = v.y;
            wr[j4 * 4 + 2] = v.z; wr[j4 * 4 + 3] = v.w;
        }
    }
    const float bg = bias[dir * GG + g];
    const bool is_g = (g >= 128 && g < 192);
    float c = 0.f;
    if (g < 64) hs[0][g] = 0.f;
    __syncthreads();

    float hreg[8];
    for (int ch = 0; ch < 125; ++ch) {
        if constexpr (KIN == 128) {
            int l = g * 4, u = l >> 7, k = l & 127;
            int s = ch * 8 + u, tt = dir ? (T_ - 1) - s : s;
            const TI* src = in + ((size_t)bb * T_ + tt) * 128 + k;
            f32x4 fv;
            if constexpr (std::is_same_v<TI, float>) fv = *(const f32x4*)src;
            else {
                ushort4 rv = *(const ushort4*)src;
                fv = (f32x4){bf2f(rv.x), bf2f(rv.y), bf2f(rv.z), bf2f(rv.w)};
            }
            *(f32x4*)&xs[u][k] = fv;
        } else {
            int u = g >> 5, k = g & 31;
            int s = ch * 8 + u, tt = dir ? (T_ - 1) - s : s;
            if constexpr (std::is_same_v<TI, float>)
                xs[u][k] = in[((size_t)bb * T_ + tt) * 32 + k];
            else
                xs[u][k] = bf2f(((const unsigned short*)in)[((size_t)bb * T_ + tt) * 32 + k]);
        }
        __syncthreads();
        #pragma unroll
        for (int u = 0; u < 8; ++u) {
            const int p = (ch * 8 + u) & 1;
            float a0 = bg, a1 = 0.f, a2 = 0.f, a3 = 0.f;
            #pragma unroll
            for (int k = 0; k < KIN; k += 4) {
                f32x4 xv = *(const f32x4*)&xs[u][k];
                a0 = fmaf(xv.x, wk[k + 0], a0); a1 = fmaf(xv.y, wk[k + 1], a1);
                a2 = fmaf(xv.z, wk[k + 2], a2); a3 = fmaf(xv.w, wk[k + 3], a3);
            }
            #pragma unroll
            for (int j = 0; j < 64; j += 4) {
                f32x4 hv = *(const f32x4*)&hs[p][j];
                a0 = fmaf(hv.x, wr[j + 0], a0); a1 = fmaf(hv.y, wr[j + 1], a1);
                a2 = fmaf(hv.z, wr[j + 2], a2); a3 = fmaf(hv.w, wr[j + 3], a3);
            }
            float a = (a0 + a1) + (a2 + a3);
            act[g] = is_g ? fast_tanh(a) : fast_sigmoid(a);
            __syncthreads();
            if (g < 64) {
                float iv = act[g], fv = act[64 + g], gv = act[128 + g], ov = act[192 + g];
                c = fmaf(fv, c, iv * gv);
                float hn = ov * fast_tanh(c);
                hs[p ^ 1][g] = hn;
                hreg[u] = hn;
            }
            __syncthreads();
        }
        if (g < 64) {
            #pragma unroll
            for (int u = 0; u < 8; ++u) {
                int s = ch * 8 + u, tt = dir ? (T_ - 1) - s : s;
                out[((size_t)bb * T_ + tt) * 128 + dir * HH + g] = (TO)hreg[u];
            }
        }
    }
}

// ---------------------------------------------------------------- heads (f32 out)
__global__ __launch_bounds__(64) void head_last(
    const float* __restrict__ hl, const float* __restrict__ wlin,
    const float* __restrict__ blin, float* __restrict__ outp) {
    const int b = blockIdx.x, tid = threadIdx.x;
    __shared__ float hv[128];
    hv[tid] = hl[(size_t)b * 128 + tid];
    hv[64 + tid] = hl[(size_t)b * 128 + 64 + tid];
    __syncthreads();
    if (tid < 54) {
        float a = blin[tid];
        #pragma unroll 4
        for (int j = 0; j < 128; ++j) a = fmaf(hv[j], wlin[tid * 128 + j], a);
        outp[b * 54 + tid] = a;
    }
}

template<typename TI>
__global__ __launch_bounds__(64) void head_kernel(
    const TI* __restrict__ fin, const float* __restrict__ wlin,
    const float* __restrict__ blin, float* __restrict__ outp) {
    const int b = blockIdx.x, tid = threadIdx.x;
    __shared__ float hv[128];
    #pragma unroll
    for (int rr = 0; rr < 2; ++rr) {
        int j = rr * 64 + tid;
        hv[j] = (float)fin[((size_t)b * T_ + (T_ - 1)) * 128 + j];
    }
    __syncthreads();
    if (tid < 54) {
        float a = blin[tid];
        #pragma unroll 4
        for (int j = 0; j < 128; ++j) a = fmaf(hv[j], wlin[tid * 128 + j], a);
        outp[b * 54 + tid] = a;
    }
}

extern "C" void kernel_launch(void* const* d_in, const int* in_sizes, int n_in,
                              void* d_out, int out_size, void* d_ws, size_t ws_size,
                              hipStream_t stream) {
    const float* x    = (const float*)d_in[0];
    const float* wihf = (const float*)d_in[1];
    const float* wihr = (const float*)d_in[2];
    const float* whh  = (const float*)d_in[3];
    const float* bih  = (const float*)d_in[4];
    const float* bhh  = (const float*)d_in[5];
    const float* wlin = (const float*)d_in[6];
    const float* blin = (const float*)d_in[7];
    float* outp = (float*)d_out;

    char* ws = (char*)d_ws;
    const size_t PB = (size_t)NB * T_ * 128 * sizeof(__bf16);  // 65,536,000
    const size_t PX = (size_t)NB * T_ * 32 * sizeof(__bf16);   // 16,384,000
    const size_t HL = (size_t)NB * 128 * sizeof(float);        //    131,072
    const size_t WSZ = 794624;
    const bool primary = ws_size >= 2 * PB + 2 * PX + HL + WSZ;  // ~164.8 MB (proven >=263)

    char* sw = primary ? (ws + 2 * PB + 2 * PX + HL) : (ws + 2 * PB);
    __bf16* w0H  = (__bf16*)(sw);             //  32,768 B
    __bf16* w0L  = (__bf16*)(sw + 32768);     //  32,768 B
    __bf16* wrH  = (__bf16*)(sw + 65536);     // 393,216 B
    __bf16* whH  = (__bf16*)(sw + 458752);    // 262,144 B
    float*  bias = (float*) (sw + 720896);    //   8,192 B
    float*  w0f  = (float*) (sw + 729088);    //  65,536 B (VALU fallback)

    prep_w<<<768, 256, 0, stream>>>(wihf, wihr, whh, bih, bhh,
                                    w0H, w0L, wrH, whH, bias, w0f);

    if (primary) {
        __bf16* A   = (__bf16*)ws;
        __bf16* B   = (__bf16*)(ws + PB);
        __bf16* xhi = (__bf16*)(ws + 2 * PB);
        __bf16* xlo = (__bf16*)(ws + 2 * PB + PX);
        float*  hl  = (float*)(ws + 2 * PB + 2 * PX);
        prep_x_ps<<<NB, 256, 0, stream>>>(x, xhi, xlo);
        const dim3 sgrid(NB / 2, 2);
        fused_scan3<1, true,  false><<<sgrid, 256, 0, stream>>>(xhi, xlo, w0H, w0L, whH, bias, A, nullptr);
        fused_scan3<4, false, false><<<sgrid, 256, 0, stream>>>(A, nullptr, wrH, nullptr,
            whH + 32768, bias + 512, B, nullptr);
        fused_scan3<4, false, false><<<sgrid, 256, 0, stream>>>(B, nullptr, wrH + 65536, nullptr,
            whH + 65536, bias + 1024, A, nullptr);
        fused_scan3<4, false, true><<<sgrid, 256, 0, stream>>>(A, nullptr, wrH + 131072, nullptr,
            whH + 98304, bias + 1536, B, hl);
        head_last<<<NB, 64, 0, stream>>>(hl, wlin, blin, outp);
    } else {
        __bf16* A = (__bf16*)ws;
        __bf16* B = (__bf16*)(ws + PB);
        __bf16* xp = (__bf16*)ws;  // aliases A; dead before A written
        prep_x_b<<<NB, 256, 0, stream>>>(x, xp);
        const dim3 vgrid(NB, 2);
        scan_valu<32, __bf16, __bf16><<<vgrid, 256, 0, stream>>>(xp, w0f, whh, bias, B);
        scan_valu<128, __bf16, __bf16><<<vgrid, 256, 0, stream>>>(B, wihr,          whh + 32768, bias + 512,  A);
        scan_valu<128, __bf16, __bf16><<<vgrid, 256, 0, stream>>>(A, wihr + 65536,  whh + 65536, bias + 1024, B);
        scan_valu<128, __bf16, __bf16><<<vgrid, 256, 0, stream>>>(B, wihr + 131072, whh + 98304, bias + 1536, A);
        head_kernel<__bf16><<<NB, 64, 0, stream>>>(A, wlin, blin, outp);
    }
}

// Round 4
// 1244.771 us; speedup vs baseline: 1.0112x; 1.0112x over previous
//
#include <hip/hip_runtime.h>
#include <hip/hip_bf16.h>
#include <type_traits>

#define T_    1000
#define NB    256
#define HH    64
#define GG    256

typedef float f32x4 __attribute__((ext_vector_type(4)));
typedef __bf16 bf16x8 __attribute__((ext_vector_type(8)));

// Barrier that does NOT drain vmcnt (plain __syncthreads emits s_waitcnt vmcnt(0)
// which would stall on global h-stores and x-prefetch every step).
__device__ __forceinline__ void barrier_lds() {
    asm volatile("s_waitcnt lgkmcnt(0)\n\ts_barrier" ::: "memory");
}

__device__ __forceinline__ float fast_sigmoid(float x) {
    float e = __expf(-x);
    return __builtin_amdgcn_rcpf(1.f + e);
}
__device__ __forceinline__ float fast_tanh(float x) {
    x = fmaxf(x, -15.f);
    float e = __expf(-2.f * x);
    return (1.f - e) * __builtin_amdgcn_rcpf(1.f + e);
}
__device__ __forceinline__ float bf2f(unsigned short u) {
    return __builtin_bit_cast(float, (unsigned)u << 16);
}

// ---------------------------------------------------------------- weight prep
__global__ void prep_w(const float* __restrict__ wihf, const float* __restrict__ wihr,
                       const float* __restrict__ whh, const float* __restrict__ bih,
                       const float* __restrict__ bhh,
                       __bf16* __restrict__ w0H, __bf16* __restrict__ w0L,
                       __bf16* __restrict__ wrH, __bf16* __restrict__ whH,
                       float* __restrict__ bias, float* __restrict__ w0f) {
    int i = blockIdx.x * 256 + threadIdx.x;
    if (i < 2 * GG * 32) {
        int k = i & 31, gd = i >> 5;
        float w = (k < 22) ? wihf[gd * 22 + k] : 0.f;
        __bf16 h = (__bf16)w;
        w0H[i] = h; w0L[i] = (__bf16)(w - (float)h);
        w0f[i] = w;
    }
    if (i < 3 * 2 * GG * 128) wrH[i] = (__bf16)wihr[i];
    if (i < 4 * 2 * GG * HH)  whH[i] = (__bf16)whh[i];
    if (i < 4 * 2 * GG)       bias[i] = bih[i] + bhh[i];
}

// ---------------------------------------------------------------- x prep, hi/lo bf16 planes (layer 0)
__global__ __launch_bounds__(256) void prep_x_ps(const float* __restrict__ x,
                                                 __bf16* __restrict__ xhi,
                                                 __bf16* __restrict__ xlo) {
    const int b = blockIdx.x;
    __shared__ float xs[22][104];
    for (int tc = 0; tc < 10; ++tc) {
        const int t0 = tc * 100;
        __syncthreads();
        for (int i = threadIdx.x; i < 22 * 100; i += 256) {
            int k = i / 100, t = i - k * 100;
            xs[k][t] = x[((size_t)b * 22 + k) * T_ + t0 + t];
        }
        __syncthreads();
        for (int i = threadIdx.x; i < 100 * 4; i += 256) {
            int t = i >> 2, p = i & 3;
            bf16x8 vh, vl;
            #pragma unroll
            for (int j = 0; j < 8; ++j) {
                int k = p * 8 + j;
                float f = (k < 22) ? xs[k][t] : 0.f;
                __bf16 h = (__bf16)f;
                vh[j] = h;
                vl[j] = (__bf16)(f - (float)h);
            }
            *(bf16x8*)(xhi + ((size_t)b * T_ + t0 + t) * 32 + p * 8) = vh;
            *(bf16x8*)(xlo + ((size_t)b * T_ + t0 + t) * 32 + p * 8) = vl;
        }
    }
}

// ---------------------------------------------------------------- x prep single bf16 plane (fallback)
__global__ __launch_bounds__(256) void prep_x_b(const float* __restrict__ x,
                                                __bf16* __restrict__ xp) {
    const int b = blockIdx.x;
    __shared__ float xs[22][104];
    for (int tc = 0; tc < 10; ++tc) {
        const int t0 = tc * 100;
        __syncthreads();
        for (int i = threadIdx.x; i < 22 * 100; i += 256) {
            int k = i / 100, t = i - k * 100;
            xs[k][t] = x[((size_t)b * 22 + k) * T_ + t0 + t];
        }
        __syncthreads();
        for (int i = threadIdx.x; i < 100 * 4; i += 256) {
            int t = i >> 2, p = i & 3;
            bf16x8 v;
            #pragma unroll
            for (int j = 0; j < 8; ++j) {
                int k = p * 8 + j;
                v[j] = (k < 22) ? (__bf16)xs[k][t] : (__bf16)0.f;
            }
            *(bf16x8*)(xp + ((size_t)b * T_ + t0 + t) * 32 + p * 8) = v;
        }
    }
}

// ---------------------------------------------------------------- MFMA fused layer, 2 chains/block (r13 shape)
// r17 = r15 structure (weights in registers, flush clumped at u==0, x-prefetch
// double-buffered at u==0, ds_swizzle c-exchange) + the r16 deltas that shorten
// the serial chain without adding LDS traffic:
//  - R-chain takes P(+bias) as MFMA C-in: gates = R[F][r] directly (no
//    extract+add junction between MFMA result and activation chain).
//  - PuA/PuB role ping-pong across groups (no 16-reg rotation copy); retired
//    accumulator re-inited from a resident bias-splat f32x4.
// r16's LDS weight streaming REVERTED: it added 2 ds_reads/step into the
// lgkmcnt(0)-before-barrier drain -> lengthened the serial path (304->315us).
template<int KCH, bool L0, bool FIN>
__global__ __launch_bounds__(256, 1) void fused_scan3(
    const __bf16* __restrict__ inA,   // (B,T,KCH*32) bf16 (hi plane if L0)
    const __bf16* __restrict__ inB,   // lo plane (iff L0)
    const __bf16* __restrict__ wihH,  // (2,256,KCH*32) bf16 hi
    const __bf16* __restrict__ wihL,  // same, lo (iff L0)
    const __bf16* __restrict__ whhH,  // (2,256,64) bf16
    const float*  __restrict__ bias,  // (2,256) f32
    __bf16* __restrict__ out,         // (B,T,128) bf16
    float* __restrict__ outF)         // (B,128) f32 last-t h (iff FIN)
{
    const int dir = blockIdx.y;
    const int b0 = blockIdx.x * 2;
    const int tid = threadIdx.x;
    const int wv = tid >> 6, lane = tid & 63;
    const int j2 = lane & 15, q = lane >> 4;
    const int ch_l = j2 >> 3;          // chain of this lane's A-row
    const int u_l = j2 & 7;            // step-in-group of this lane's A-row
    constexpr int KIN = KCH * 32;

    __shared__ __align__(16) __bf16 hbuf[2][2][80]; // [parity][chain][j pad]

    bf16x8 wf[4][KCH], wfl[4][L0 ? KCH : 1];
    bf16x8 whf[4][2];
    f32x4 bias4[4];
    #pragma unroll
    for (int F = 0; F < 4; ++F) {
        const int g = (F * 4 + wv) * 16 + j2;
        float bg = bias[dir * GG + g];
        bias4[F] = (f32x4){bg, bg, bg, bg};
        #pragma unroll
        for (int ks = 0; ks < KCH; ++ks) {
            wf[F][ks] = *(const bf16x8*)(wihH + ((size_t)dir * GG + g) * KIN + ks * 32 + q * 8);
            if constexpr (L0)
                wfl[F][ks] = *(const bf16x8*)(wihL + ((size_t)dir * GG + g) * KIN + ks * 32 + q * 8);
        }
        #pragma unroll
        for (int ks = 0; ks < 2; ++ks)
            whf[F][ks] = *(const bf16x8*)(whhH + ((size_t)dir * GG + g) * HH + ks * 32 + q * 8);
    }
    if (tid < 64) {
        hbuf[1][0][tid] = (__bf16)0.f;
        hbuf[1][1][tid] = (__bf16)0.f;
    }
    __syncthreads();

    // double-buffered x fragments: A holds even-group x, B holds odd-group x
    bf16x8 xfA[KCH], xfB[KCH];
    bf16x8 xlA[L0 ? KCH : 1], xlB[L0 ? KCH : 1];
    auto issue_x = [&](int grp, auto& dh, auto& dl) {
        int s = grp * 8 + u_l;
        if (s > T_ - 1) s = T_ - 1;
        int tt = dir ? (T_ - 1) - s : s;
        const __bf16* ph = inA + ((size_t)(b0 + ch_l) * T_ + tt) * KIN + q * 8;
        #pragma unroll
        for (int ks = 0; ks < KCH; ++ks)
            dh[ks] = *(const bf16x8*)(ph + ks * 32);
        if constexpr (L0) {
            const __bf16* pl = inB + ((size_t)(b0 + ch_l) * T_ + tt) * KIN + q * 8;
            #pragma unroll
            for (int ks = 0; ks < KCH; ++ks)
                dl[ks] = *(const bf16x8*)(pl + ks * 32);
        }
    };

    // ---- prologue: P(0) into PuA (bias pre-folded), prefetch x(1) into xfB
    f32x4 PuA[4], PuB[4];
    #pragma unroll
    for (int F = 0; F < 4; ++F) { PuA[F] = bias4[F]; PuB[F] = bias4[F]; }
    issue_x(0, xfA, xlA);
    #pragma unroll
    for (int ks = 0; ks < KCH; ++ks)
        #pragma unroll
        for (int F = 0; F < 4; ++F)
            PuA[F] = __builtin_amdgcn_mfma_f32_16x16x32_bf16(xfA[ks], wf[F][ks], PuA[F], 0, 0, 0);
    if constexpr (L0) {
        #pragma unroll
        for (int ks = 0; ks < KCH; ++ks)
            #pragma unroll
            for (int F = 0; F < 4; ++F)
                PuA[F] = __builtin_amdgcn_mfma_f32_16x16x32_bf16(xlA[ks], wf[F][ks], PuA[F], 0, 0, 0);
        #pragma unroll
        for (int ks = 0; ks < KCH; ++ks)
            #pragma unroll
            for (int F = 0; F < 4; ++F)
                PuA[F] = __builtin_amdgcn_mfma_f32_16x16x32_bf16(xfA[ks], wfl[F][ks], PuA[F], 0, 0, 0);
    }
    issue_x(1, xfB, xlB);

    float hsA[8], hsB[8];
    float creg = 0.f;

    // deferred h flush for group g: 8 bf16 stores with compile-time offsets
    auto FLUSH = [&](int g, float (&hs)[8]) {
        const int ch = q >> 1;
        const size_t col = (size_t)dir * HH + wv * 16 + j2;
        if (dir == 0) {
            __bf16* base = out + ((size_t)(b0 + ch) * T_ + g * 8) * 128 + col;
            #pragma unroll
            for (int u = 0; u < 8; ++u)
                if ((q & 1) == (u >> 2)) base[u * 128] = (__bf16)hs[u];
            if constexpr (FIN)
                if (g == 124 && (q & 1) == 1)
                    outF[(size_t)(b0 + ch) * 128 + col] = hs[7];
        } else {
            __bf16* base = out + ((size_t)(b0 + ch) * T_ + ((T_ - 1) - g * 8)) * 128 + col;
            #pragma unroll
            for (int u = 0; u < 8; ++u)
                if ((q & 1) == (u >> 2)) *(base - u * 128) = (__bf16)hs[u];
            if constexpr (FIN)
                if (g == 0 && (q & 1) == 0)
                    outF[(size_t)(b0 + ch) * 128 + col] = hs[0];
        }
    };

    // one 8-step group; xc = x(grp+1) (feeds Pnx), xn = buffer for x(grp+2).
    // Pc = P(grp)+bias, consumed as R C-in; Pnx accumulates P(grp+1).
    // hsC = this group's h regs; hsP = previous group's (flushed at u==0).
    auto GROUP = [&](int grp, auto& xcH, auto& xnH, auto& xcL, auto& xnL,
                     f32x4 (&Pc)[4], f32x4 (&Pnx)[4],
                     float (&hsC)[8], float (&hsP)[8]) {
        #pragma unroll
        for (int u = 0; u < 8; ++u) {
            const int rp = (u + 1) & 1;   // grp*8 even -> parity compile-time
            // ds_reads first...
            bf16x8 ah0 = *(const bf16x8*)&hbuf[rp][ch_l][q * 8];
            bf16x8 ah1 = *(const bf16x8*)&hbuf[rp][ch_l][32 + q * 8];

            // ...deferred flush VALU+stores fill the ds latency at u==0
            if (u == 0 && grp > 0) FLUSH(grp - 1, hsP);

            // Pn pipeline (independent -> fills ds latency)
            if constexpr (!L0) {
                const int ks = u >> 1;
                const int Fb = (u & 1) * 2;
                Pnx[Fb]     = __builtin_amdgcn_mfma_f32_16x16x32_bf16(xcH[ks], wf[Fb][ks],     Pnx[Fb], 0, 0, 0);
                Pnx[Fb + 1] = __builtin_amdgcn_mfma_f32_16x16x32_bf16(xcH[ks], wf[Fb + 1][ks], Pnx[Fb + 1], 0, 0, 0);
            } else {
                if (u == 0) {
                    #pragma unroll
                    for (int F = 0; F < 4; ++F)
                        Pnx[F] = __builtin_amdgcn_mfma_f32_16x16x32_bf16(xcH[0], wf[F][0], Pnx[F], 0, 0, 0);
                } else if (u == 1) {
                    #pragma unroll
                    for (int F = 0; F < 4; ++F)
                        Pnx[F] = __builtin_amdgcn_mfma_f32_16x16x32_bf16(xcL[0], wf[F][0], Pnx[F], 0, 0, 0);
                } else if (u == 2) {
                    #pragma unroll
                    for (int F = 0; F < 4; ++F)
                        Pnx[F] = __builtin_amdgcn_mfma_f32_16x16x32_bf16(xcH[0], wfl[F][0], Pnx[F], 0, 0, 0);
                }
            }

            // recurrent MFMAs with P+bias as C-in: gates come out of one acc quad
            f32x4 R[4];
            #pragma unroll
            for (int F = 0; F < 4; ++F) {
                f32x4 t = __builtin_amdgcn_mfma_f32_16x16x32_bf16(ah0, whf[F][0], Pc[F], 0, 0, 0);
                R[F] = __builtin_amdgcn_mfma_f32_16x16x32_bf16(ah1, whf[F][1], t, 0, 0, 0);
            }

            // x prefetch for grp+2 (fire-and-forget; consumed ~2 groups later)
            if (u == 0) issue_x(grp + 2, xnH, xnL);

            const int r = u & 3;
            const int ch = q >> 1;
            float cold = creg;
            float iv = R[0][r];
            float fv = R[1][r];
            float gv = R[2][r];
            float ov = R[3][r];
            float cn = fast_sigmoid(fv) * cold + fast_sigmoid(iv) * fast_tanh(gv);
            float hn = fast_sigmoid(ov) * fast_tanh(cn);
            // c-handoff between q-lane-halves via lane^16 swizzle
            if (u == 3 || u == 7)
                creg = __builtin_bit_cast(float,
                        __builtin_amdgcn_ds_swizzle(__builtin_bit_cast(int, cn), 0x401F));
            else
                creg = cn;
            const bool owner = ((q & 1) == (u >> 2));
            if (owner) {
                hbuf[u & 1][ch][wv * 16 + j2] = (__bf16)hn;
                hsC[u] = hn;
            }
            barrier_lds();
        }
        // retire Pc: becomes next group's fresh accumulator (bias pre-folded)
        #pragma unroll
        for (int F = 0; F < 4; ++F) Pc[F] = bias4[F];
    };

    for (int g2 = 0; g2 < 62; ++g2) {
        GROUP(g2 * 2,     xfB, xfA, xlB, xlA, PuA, PuB, hsA, hsB);
        GROUP(g2 * 2 + 1, xfA, xfB, xlA, xlB, PuB, PuA, hsB, hsA);
    }
    GROUP(124, xfB, xfA, xlB, xlA, PuA, PuB, hsA, hsB);
    FLUSH(124, hsA);
}

// ---------------------------------------------------------------- VALU fallback scan (r7-proven)
template<int KIN, typename TI, typename TO>
__global__ __launch_bounds__(256, 2) void scan_valu(
    const TI* __restrict__ in, const float* __restrict__ wih,
    const float* __restrict__ whh, const float* __restrict__ bias,
    TO* __restrict__ out)
{
    const int dir = blockIdx.y, bb = blockIdx.x, g = threadIdx.x;
    __shared__ __align__(16) float xs[8][KIN];
    __shared__ __align__(16) float act[256];
    __shared__ __align__(16) float hs[2][64];

    float wk[KIN], wr[64];
    {
        const float* wp = wih + (size_t)(dir * GG + g) * KIN;
        #pragma unroll
        for (int k4 = 0; k4 < KIN / 4; ++k4) {
            f32x4 v = *(const f32x4*)(wp + k4 * 4);
            wk[k4 * 4 + 0] = v.x; wk[k4 * 4 + 1] = v.y;
            wk[k4 * 4 + 2] = v.z; wk[k4 * 4 + 3] = v.w;
        }
        const float* rp = whh + (size_t)(dir * GG + g) * HH;
        #pragma unroll
        for (int j4 = 0; j4 < 16; ++j4) {
            f32x4 v = *(const f32x4*)(rp + j4 * 4);
            wr[j4 * 4 + 0] = v.x; wr[j4 * 4 + 1] = v.y;
            wr[j4 * 4 + 2] = v.z; wr[j4 * 4 + 3] = v.w;
        }
    }
    const float bg = bias[dir * GG + g];
    const bool is_g = (g >= 128 && g < 192);
    float c = 0.f;
    if (g < 64) hs[0][g] = 0.f;
    __syncthreads();

    float hreg[8];
    for (int ch = 0; ch < 125; ++ch) {
        if constexpr (KIN == 128) {
            int l = g * 4, u = l >> 7, k = l & 127;
            int s = ch * 8 + u, tt = dir ? (T_ - 1) - s : s;
            const TI* src = in + ((size_t)bb * T_ + tt) * 128 + k;
            f32x4 fv;
            if constexpr (std::is_same_v<TI, float>) fv = *(const f32x4*)src;
            else {
                ushort4 rv = *(const ushort4*)src;
                fv = (f32x4){bf2f(rv.x), bf2f(rv.y), bf2f(rv.z), bf2f(rv.w)};
            }
            *(f32x4*)&xs[u][k] = fv;
        } else {
            int u = g >> 5, k = g & 31;
            int s = ch * 8 + u, tt = dir ? (T_ - 1) - s : s;
            if constexpr (std::is_same_v<TI, float>)
                xs[u][k] = in[((size_t)bb * T_ + tt) * 32 + k];
            else
                xs[u][k] = bf2f(((const unsigned short*)in)[((size_t)bb * T_ + tt) * 32 + k]);
        }
        __syncthreads();
        #pragma unroll
        for (int u = 0; u < 8; ++u) {
            const int p = (ch * 8 + u) & 1;
            float a0 = bg, a1 = 0.f, a2 = 0.f, a3 = 0.f;
            #pragma unroll
            for (int k = 0; k < KIN; k += 4) {
                f32x4 xv = *(const f32x4*)&xs[u][k];
                a0 = fmaf(xv.x, wk[k + 0], a0); a1 = fmaf(xv.y, wk[k + 1], a1);
                a2 = fmaf(xv.z, wk[k + 2], a2); a3 = fmaf(xv.w, wk[k + 3], a3);
            }
            #pragma unroll
            for (int j = 0; j < 64; j += 4) {
                f32x4 hv = *(const f32x4*)&hs[p][j];
                a0 = fmaf(hv.x, wr[j + 0], a0); a1 = fmaf(hv.y, wr[j + 1], a1);
                a2 = fmaf(hv.z, wr[j + 2], a2); a3 = fmaf(hv.w, wr[j + 3], a3);
            }
            float a = (a0 + a1) + (a2 + a3);
            act[g] = is_g ? fast_tanh(a) : fast_sigmoid(a);
            __syncthreads();
            if (g < 64) {
                float iv = act[g], fv = act[64 + g], gv = act[128 + g], ov = act[192 + g];
                c = fmaf(fv, c, iv * gv);
                float hn = ov * fast_tanh(c);
                hs[p ^ 1][g] = hn;
                hreg[u] = hn;
            }
            __syncthreads();
        }
        if (g < 64) {
            #pragma unroll
            for (int u = 0; u < 8; ++u) {
                int s = ch * 8 + u, tt = dir ? (T_ - 1) - s : s;
                out[((size_t)bb * T_ + tt) * 128 + dir * HH + g] = (TO)hreg[u];
            }
        }
    }
}

// ---------------------------------------------------------------- heads (f32 out)
__global__ __launch_bounds__(64) void head_last(
    const float* __restrict__ hl, const float* __restrict__ wlin,
    const float* __restrict__ blin, float* __restrict__ outp) {
    const int b = blockIdx.x, tid = threadIdx.x;
    __shared__ float hv[128];
    hv[tid] = hl[(size_t)b * 128 + tid];
    hv[64 + tid] = hl[(size_t)b * 128 + 64 + tid];
    __syncthreads();
    if (tid < 54) {
        float a = blin[tid];
        #pragma unroll 4
        for (int j = 0; j < 128; ++j) a = fmaf(hv[j], wlin[tid * 128 + j], a);
        outp[b * 54 + tid] = a;
    }
}

template<typename TI>
__global__ __launch_bounds__(64) void head_kernel(
    const TI* __restrict__ fin, const float* __restrict__ wlin,
    const float* __restrict__ blin, float* __restrict__ outp) {
    const int b = blockIdx.x, tid = threadIdx.x;
    __shared__ float hv[128];
    #pragma unroll
    for (int rr = 0; rr < 2; ++rr) {
        int j = rr * 64 + tid;
        hv[j] = (float)fin[((size_t)b * T_ + (T_ - 1)) * 128 + j];
    }
    __syncthreads();
    if (tid < 54) {
        float a = blin[tid];
        #pragma unroll 4
        for (int j = 0; j < 128; ++j) a = fmaf(hv[j], wlin[tid * 128 + j], a);
        outp[b * 54 + tid] = a;
    }
}

extern "C" void kernel_launch(void* const* d_in, const int* in_sizes, int n_in,
                              void* d_out, int out_size, void* d_ws, size_t ws_size,
                              hipStream_t stream) {
    const float* x    = (const float*)d_in[0];
    const float* wihf = (const float*)d_in[1];
    const float* wihr = (const float*)d_in[2];
    const float* whh  = (const float*)d_in[3];
    const float* bih  = (const float*)d_in[4];
    const float* bhh  = (const float*)d_in[5];
    const float* wlin = (const float*)d_in[6];
    const float* blin = (const float*)d_in[7];
    float* outp = (float*)d_out;

    char* ws = (char*)d_ws;
    const size_t PB = (size_t)NB * T_ * 128 * sizeof(__bf16);  // 65,536,000
    const size_t PX = (size_t)NB * T_ * 32 * sizeof(__bf16);   // 16,384,000
    const size_t HL = (size_t)NB * 128 * sizeof(float);        //    131,072
    const size_t WSZ = 794624;
    const bool primary = ws_size >= 2 * PB + 2 * PX + HL + WSZ;  // ~164.8 MB (proven >=263)

    char* sw = primary ? (ws + 2 * PB + 2 * PX + HL) : (ws + 2 * PB);
    __bf16* w0H  = (__bf16*)(sw);             //  32,768 B
    __bf16* w0L  = (__bf16*)(sw + 32768);     //  32,768 B
    __bf16* wrH  = (__bf16*)(sw + 65536);     // 393,216 B
    __bf16* whH  = (__bf16*)(sw + 458752);    // 262,144 B
    float*  bias = (float*) (sw + 720896);    //   8,192 B
    float*  w0f  = (float*) (sw + 729088);    //  65,536 B (VALU fallback)

    prep_w<<<768, 256, 0, stream>>>(wihf, wihr, whh, bih, bhh,
                                    w0H, w0L, wrH, whH, bias, w0f);

    if (primary) {
        __bf16* A   = (__bf16*)ws;
        __bf16* B   = (__bf16*)(ws + PB);
        __bf16* xhi = (__bf16*)(ws + 2 * PB);
        __bf16* xlo = (__bf16*)(ws + 2 * PB + PX);
        float*  hl  = (float*)(ws + 2 * PB + 2 * PX);
        prep_x_ps<<<NB, 256, 0, stream>>>(x, xhi, xlo);
        const dim3 sgrid(NB / 2, 2);
        fused_scan3<1, true,  false><<<sgrid, 256, 0, stream>>>(xhi, xlo, w0H, w0L, whH, bias, A, nullptr);
        fused_scan3<4, false, false><<<sgrid, 256, 0, stream>>>(A, nullptr, wrH, nullptr,
            whH + 32768, bias + 512, B, nullptr);
        fused_scan3<4, false, false><<<sgrid, 256, 0, stream>>>(B, nullptr, wrH + 65536, nullptr,
            whH + 65536, bias + 1024, A, nullptr);
        fused_scan3<4, false, true><<<sgrid, 256, 0, stream>>>(A, nullptr, wrH + 131072, nullptr,
            whH + 98304, bias + 1536, B, hl);
        head_last<<<NB, 64, 0, stream>>>(hl, wlin, blin, outp);
    } else {
        __bf16* A = (__bf16*)ws;
        __bf16* B = (__bf16*)(ws + PB);
        __bf16* xp = (__bf16*)ws;  // aliases A; dead before A written
        prep_x_b<<<NB, 256, 0, stream>>>(x, xp);
        const dim3 vgrid(NB, 2);
        scan_valu<32, __bf16, __bf16><<<vgrid, 256, 0, stream>>>(xp, w0f, whh, bias, B);
        scan_valu<128, __bf16, __bf16><<<vgrid, 256, 0, stream>>>(B, wihr,          whh + 32768, bias + 512,  A);
        scan_valu<128, __bf16, __bf16><<<vgrid, 256, 0, stream>>>(A, wihr + 65536,  whh + 65536, bias + 1024, B);
        scan_valu<128, __bf16, __bf16><<<vgrid, 256, 0, stream>>>(B, wihr + 131072, whh + 98304, bias + 1536, A);
        head_kernel<__bf16><<<NB, 64, 0, stream>>>(A, wlin, blin, outp);
    }
}